// Round 3
// baseline (119.256 us; speedup 1.0000x reference)
//
#include <hip/hip_runtime.h>

// out[b,s,i] = w * x[b,s,i] + (1-w) * x[b,s,(i+1) % C],  C = 4096.
// Two float4 groups per thread: neighbor of group 2h is v1.x (register-local);
// only group 2h+1 needs the cross-lane shuffle / row-wrap fallback.

typedef float f32x4 __attribute__((ext_vector_type(4)));

#define C_MASK 4095

__global__ __launch_bounds__(256) void NormalizedCirculantMask2_kernel(
    const float* __restrict__ x,
    const float* __restrict__ wptr,
    float* __restrict__ out,
    int total8)   // number of float4 PAIRS
{
    const float w  = wptr[0];
    const float wc = 1.0f - w;
    const int lane = threadIdx.x & 63;

    int stride = gridDim.x * blockDim.x;
    for (int h = blockIdx.x * blockDim.x + threadIdx.x; h < total8; h += stride) {
        const int g0 = 2 * h;          // even group: col0 <= 4088, never wraps
        const int g1 = g0 + 1;

        f32x4 v0 = __builtin_nontemporal_load(reinterpret_cast<const f32x4*>(x) + g0);
        f32x4 v1 = __builtin_nontemporal_load(reinterpret_cast<const f32x4*>(x) + g1);

        // neighbor of g1's last element = v0.x of the NEXT lane (group g1+1 = 2(h+1))
        float vn = __shfl(v0.x, lane + 1);   // garbage for lane 63, fixed below

        float e1;
        if ((lane == 63) || ((h & 511) == 511)) {
            // fallback: element (4*g1 + 4) mod 4096 within g1's row
            int row_base = (g1 >> 10) << 12;         // row * 4096
            int col0     = (g1 & 1023) << 2;
            e1 = x[row_base + ((col0 + 4) & C_MASK)];
        } else {
            e1 = vn;
        }

        f32x4 o0, o1;
        o0.x = w * v0.x + wc * v0.y;
        o0.y = w * v0.y + wc * v0.z;
        o0.z = w * v0.z + wc * v0.w;
        o0.w = w * v0.w + wc * v1.x;   // register-local neighbor

        o1.x = w * v1.x + wc * v1.y;
        o1.y = w * v1.y + wc * v1.z;
        o1.z = w * v1.z + wc * v1.w;
        o1.w = w * v1.w + wc * e1;

        __builtin_nontemporal_store(o0, reinterpret_cast<f32x4*>(out) + g0);
        __builtin_nontemporal_store(o1, reinterpret_cast<f32x4*>(out) + g1);
    }
}

extern "C" void kernel_launch(void* const* d_in, const int* in_sizes, int n_in,
                              void* d_out, int out_size, void* d_ws, size_t ws_size,
                              hipStream_t stream)
{
    const float* x    = (const float*)d_in[0];
    const float* wptr = (const float*)d_in[1];
    float* out        = (float*)d_out;

    int total8 = out_size / 8;            // 8,388,608 float4 pairs
    int block  = 256;
    int grid   = 2048;                    // 256 CUs x 8 blocks, grid-stride

    NormalizedCirculantMask2_kernel<<<grid, block, 0, stream>>>(x, wptr, out, total8);
}

// Round 4
// 94.786 us; speedup vs baseline: 1.2582x; 1.2582x over previous
//
#include <hip/hip_runtime.h>

// out[b,s,i] = w * x[b,s,i] + (1-w) * x[b,s,(i+1) % C],  C = 4096.
// One circular row (4096 floats = 16 float4 groups x 64 lanes) per wave:
// all wrap neighbors are in-wave (shfl / readlane), no fallback loads,
// no divergence. Every load/store is a lane-contiguous 1KB segment.

typedef float f32x4 __attribute__((ext_vector_type(4)));

__global__ __launch_bounds__(256) void NormalizedCirculantMask2_kernel(
    const float* __restrict__ x,
    const float* __restrict__ wptr,
    float* __restrict__ out,
    int nrows)
{
    const float w  = wptr[0];
    const float wc = 1.0f - w;
    const int lane  = threadIdx.x & 63;
    const int wib   = threadIdx.x >> 6;                    // wave in block
    const int wpb   = blockDim.x >> 6;                     // waves per block
    int wave_id     = blockIdx.x * wpb + wib;
    int nwaves      = gridDim.x * wpb;

    for (int row = wave_id; row < nrows; row += nwaves) {
        const f32x4* xr = reinterpret_cast<const f32x4*>(x) + (size_t)row * 1024;
        f32x4*       orp = reinterpret_cast<f32x4*>(out)   + (size_t)row * 1024;

        f32x4 v[16];
        #pragma unroll
        for (int j = 0; j < 16; ++j)
            v[j] = __builtin_nontemporal_load(xr + j * 64 + lane);

        #pragma unroll
        for (int j = 0; j < 16; ++j) {
            // neighbor of this group's last element = next group's first element
            float e = __shfl(v[j].x, lane + 1);            // lane 63: garbage
            // lane 63's next group is (j+1)-th group's lane 0 (wraps j=15 -> j=0,
            // which is exactly the circular wrap to element 0 of the row)
            int f_bits = __builtin_amdgcn_readlane(
                             __builtin_bit_cast(int, v[(j + 1) & 15].x), 0);
            float first = __builtin_bit_cast(float, f_bits);
            e = (lane == 63) ? first : e;                  // cndmask, no branch

            f32x4 o;
            o.x = w * v[j].x + wc * v[j].y;
            o.y = w * v[j].y + wc * v[j].z;
            o.z = w * v[j].z + wc * v[j].w;
            o.w = w * v[j].w + wc * e;
            __builtin_nontemporal_store(o, orp + j * 64 + lane);
        }
    }
}

extern "C" void kernel_launch(void* const* d_in, const int* in_sizes, int n_in,
                              void* d_out, int out_size, void* d_ws, size_t ws_size,
                              hipStream_t stream)
{
    const float* x    = (const float*)d_in[0];
    const float* wptr = (const float*)d_in[1];
    float* out        = (float*)d_out;

    int nrows = out_size / 4096;          // 16384 rows of C=4096
    int block = 256;                      // 4 waves/block
    int grid  = 2048;                     // 8192 waves, 2 rows each

    NormalizedCirculantMask2_kernel<<<grid, block, 0, stream>>>(x, wptr, out, nrows);
}